// Round 5
// baseline (558.448 us; speedup 1.0000x reference)
//
#include <hip/hip_runtime.h>
#include <hip/hip_bf16.h>

typedef __hip_bfloat16 bf16;
typedef __attribute__((ext_vector_type(8))) short s16x8;   // 8 bf16 (4 VGPRs) MFMA frag
typedef __attribute__((ext_vector_type(4))) float f32x4;   // MFMA accumulator

#define B_ 2
#define S_ 4096
#define H_ 2048
#define R_ 2048
#define M_ 8192      // B*S
#define NB_ 16
#define BW_ 128
#define CHUNK 64     // scan chunk length
#define NCH 64       // S/CHUNK

__device__ __forceinline__ short f2b_s(float f) {
    return (short)__builtin_bit_cast(unsigned short, __float2bfloat16(f));
}
__device__ __forceinline__ float b2f_s(short s) {
    unsigned int u = ((unsigned int)(unsigned short)s) << 16;
    return __builtin_bit_cast(float, u);
}
__device__ __forceinline__ float sigm_fast(float x) { return 1.f / (1.f + __expf(-x)); }

// async global->LDS, 16B per lane; LDS dest must be wave-uniform base + lane*16
__device__ __forceinline__ void async_g2l(const void* g, void* l) {
    __builtin_amdgcn_global_load_lds((const __attribute__((address_space(1))) void*)g,
                                     (__attribute__((address_space(3))) void*)l, 16, 0, 0);
}

// ---------------- merged cast fp32 -> bf16 for x / Wxy / Wres ----------------
// unit = 8 elems. x: 2097152 units, Wxy: 1048576, Wres: 524288 -> 3670016 total.
__global__ __launch_bounds__(256) void cast_all(const float* __restrict__ x,
                                                const float* __restrict__ wxy,
                                                const float* __restrict__ wres,
                                                bf16* __restrict__ xbf,
                                                bf16* __restrict__ wxyb,
                                                bf16* __restrict__ wresb) {
    int idx = blockIdx.x * 256 + threadIdx.x;
    const float* in; bf16* out; int off;
    if (idx < 2097152)      { in = x;    out = xbf;   off = idx; }
    else if (idx < 3145728) { in = wxy;  out = wxyb;  off = idx - 2097152; }
    else                    { in = wres; out = wresb; off = idx - 3145728; }
    size_t i8 = (size_t)off * 8;
    float4 v0 = *(const float4*)(in + i8);
    float4 v1 = *(const float4*)(in + i8 + 4);
    s16x8 o;
    o[0] = f2b_s(v0.x); o[1] = f2b_s(v0.y); o[2] = f2b_s(v0.z); o[3] = f2b_s(v0.w);
    o[4] = f2b_s(v1.x); o[5] = f2b_s(v1.y); o[6] = f2b_s(v1.z); o[7] = f2b_s(v1.w);
    *(s16x8*)(out + i8) = o;
}

// ---------------- transpose-cast gate weights via LDS tile ----------------
// grid 32: p = blk>>4, n = blk&15. wT[p][n][j][i] = w_p[n][i][j], bf16.
__global__ __launch_bounds__(256) void wcast_T(const float* __restrict__ igw,
                                               const float* __restrict__ agw,
                                               bf16* __restrict__ wT) {
    __shared__ float tile[128 * 129];
    int blk = blockIdx.x;
    int p = blk >> 4, n = blk & 15;
    const float* w = (p ? agw : igw) + (size_t)n * 16384;   // [i][j] row-major
    int tid = threadIdx.x;
#pragma unroll
    for (int it = 0; it < 64; ++it) {
        int u = it * 256 + tid;           // element: i = u>>7, j = u&127
        tile[(u >> 7) * 129 + (u & 127)] = w[u];
    }
    __syncthreads();
    bf16* o = wT + (size_t)blk * 16384;
#pragma unroll
    for (int it = 0; it < 64; ++it) {
        int u = it * 256 + tid;           // output elem: j = u>>7, i = u&127
        o[u] = __float2bfloat16(tile[(u & 127) * 129 + (u >> 7)]);
    }
}

// ---------------- sp8[r] = 8*softplus(a_param[r]) ----------------
__global__ __launch_bounds__(256) void sp8_kernel(const float* __restrict__ apar,
                                                  float* __restrict__ sp8) {
    int r = blockIdx.x * 256 + threadIdx.x;
    float ap = apar[r];
    sp8[r] = 8.f * (ap > 20.f ? ap : log1pf(expf(ap)));
}

// ---------------- generic NT GEMM: C[M,N] = A[M,K] * B[N,K]^T, bf16 in, OutT out ----
// 128x128 tile, BK=64, 4 waves 2x2, 64x64/wave, 16x16x32 MFMA, XOR-swizzled LDS,
// global_load_lds width=16 staging. launch_bounds(256,5): 5 blocks/CU (LDS 32K*5=160K).
__device__ __forceinline__ void store_c(float* p, float v) { *p = v; }
__device__ __forceinline__ void store_c(bf16* p, float v) { *p = __float2bfloat16(v); }

template <typename OutT>
__global__ __launch_bounds__(256, 5) void gemm_bt(const bf16* __restrict__ A,
                                                  const bf16* __restrict__ Bm,
                                                  OutT* __restrict__ C,
                                                  int K, int lda, int ldb, int ldc) {
    __shared__ __align__(16) short As[128 * 64];
    __shared__ __align__(16) short Bs[128 * 64];
    const int tid = threadIdx.x;
    const int lane = tid & 63, wave = tid >> 6;
    const int waveM = wave >> 1, waveN = wave & 1;
    const int mBase = blockIdx.y * 128, nBase = blockIdx.x * 128;
    const int fm = lane & 15, q = lane >> 4;

    f32x4 acc[4][4];
#pragma unroll
    for (int i = 0; i < 4; ++i)
#pragma unroll
        for (int j = 0; j < 4; ++j) acc[i][j] = (f32x4){0.f, 0.f, 0.f, 0.f};

    for (int k0 = 0; k0 < K; k0 += 64) {
        __syncthreads();
#pragma unroll
        for (int it = 0; it < 4; ++it) {
            int off = it * 4096 + tid * 16;          // byte offset in tile (lane-contig)
            int r = off >> 7;                        // row
            int g = ((off & 127) >> 4) ^ (r & 7);    // source k-group for this slot
            async_g2l(A + (size_t)(mBase + r) * lda + k0 + g * 8, (char*)As + off);
            async_g2l(Bm + (size_t)(nBase + r) * ldb + k0 + g * 8, (char*)Bs + off);
        }
        __syncthreads();
#pragma unroll
        for (int s = 0; s < 2; ++s) {
            s16x8 af[4], bfr[4];
#pragma unroll
            for (int i = 0; i < 4; ++i) {
                int row = waveM * 64 + i * 16 + fm;
                af[i] = *(const s16x8*)((char*)As + row * 128 + ((((s << 2) + q) ^ (row & 7)) << 4));
                int col = waveN * 64 + i * 16 + fm;
                bfr[i] = *(const s16x8*)((char*)Bs + col * 128 + ((((s << 2) + q) ^ (col & 7)) << 4));
            }
#pragma unroll
            for (int i = 0; i < 4; ++i)
#pragma unroll
                for (int j = 0; j < 4; ++j)
                    acc[i][j] = __builtin_amdgcn_mfma_f32_16x16x32_bf16(af[i], bfr[j], acc[i][j], 0, 0, 0);
        }
    }
    // C/D layout: col=lane&15, row=q*4+reg (m89/m91-verified)
#pragma unroll
    for (int i = 0; i < 4; ++i) {
        int rowg = mBase + waveM * 64 + i * 16 + q * 4;
#pragma unroll
        for (int j = 0; j < 4; ++j) {
            int colg = nBase + waveN * 64 + j * 16 + fm;
#pragma unroll
            for (int rr = 0; rr < 4; ++rr)
                store_c(C + (size_t)(rowg + rr) * ldc + colg, acc[i][j][rr]);
        }
    }
}

// ------- fused: causal conv + block-diag dual gate GEMM + RG-LRU + chunk scan -------
// grid (NB_, M_/64): one block = one (batch, 64-step chunk, 128-channel block).
// Stages 67 rows of xy (conv window), computes xc in LDS, runs both gate GEMMs,
// writes la (bf16), nx (bf16), chunk summaries Ach/Hla (fp32).
__global__ __launch_bounds__(256) void gate_kernel(const bf16* __restrict__ xy,
                                                   const float* __restrict__ cw,
                                                   const float* __restrict__ cb,
                                                   const bf16* __restrict__ wT,
                                                   const float* __restrict__ igb,
                                                   const float* __restrict__ agb,
                                                   const float* __restrict__ sp8,
                                                   bf16* __restrict__ la_out,
                                                   bf16* __restrict__ nx_out,
                                                   float* __restrict__ Ach,
                                                   float* __restrict__ Hla) {
    __shared__ __align__(16) short As[64 * 128];     // 16 KB; xc tile -> nx tile
    __shared__ __align__(16) char  Wmem[128 * 256];  // 32 KB; Xs raw -> W tile -> a[64][128] f32
    short* Xs   = (short*)Wmem;                      // 67 rows x 128 shorts (raw xy window)
    short* Ws   = (short*)Wmem;
    float* a_sh = (float*)Wmem;
    const int n = blockIdx.x;
    const int mBase = blockIdx.y * 64;
    const int tid = threadIdx.x;
    const int lane = tid & 63, wave = tid >> 6;
    const int fm = lane & 15, q = lane >> 4;
    const int t0 = mBase & (S_ - 1);

    // 1. stage xy window: rows rr=0..66 <-> m = mBase + rr - 3 (zero outside batch)
#pragma unroll
    for (int it = 0; it < 5; ++it) {
        int u = it * 256 + tid;              // (rr, gg): rr = u>>4, gg = u&15
        if (u < 67 * 16) {
            int rr = u >> 4, gg = u & 15;
            s16x8 v = (s16x8){0, 0, 0, 0, 0, 0, 0, 0};
            if (t0 != 0 || rr >= 3) {
                int m = mBase + rr - 3;
                v = *(const s16x8*)(xy + (size_t)m * 4096 + n * BW_ + gg * 8);
            }
            *(s16x8*)((char*)Xs + u * 16) = v;
        }
    }
    __syncthreads();

    // 2. conv into As (swizzled bf16): thread = (col, row-half), sliding 4-tap window
    {
        int col = tid & 127, rh = tid >> 7;
        int rbase = n * BW_ + col;
        float w0c = cw[rbase], w1c = cw[R_ + rbase], w2c = cw[2 * R_ + rbase],
              w3c = cw[3 * R_ + rbase];
        float bc = cb[rbase];
        int r0 = rh * 32;
        float xm3 = b2f_s(Xs[(r0 + 0) * 128 + col]);
        float xm2 = b2f_s(Xs[(r0 + 1) * 128 + col]);
        float xm1 = b2f_s(Xs[(r0 + 2) * 128 + col]);
#pragma unroll
        for (int rw = 0; rw < 32; ++rw) {
            int row = r0 + rw;
            float x0 = b2f_s(Xs[(row + 3) * 128 + col]);
            float v = bc + w0c * xm3 + w1c * xm2 + w2c * xm1 + w3c * x0;
            xm3 = xm2; xm2 = xm1; xm1 = x0;
            *(short*)((char*)As + row * 256 + ((((col >> 3)) ^ (row & 15)) << 4) +
                      (col & 7) * 2) = f2b_s(v);
        }
    }
    __syncthreads();   // As ready; Xs region dead

    // 3. stage Ws for input gate
    const bf16* w0 = wT + (size_t)n * 16384;
#pragma unroll
    for (int it = 0; it < 8; ++it) {
        int off = it * 4096 + tid * 16;
        int j = off >> 8;
        int g = ((off & 255) >> 4) ^ (j & 15);
        async_g2l(w0 + j * 128 + g * 8, (char*)Ws + off);
    }
    __syncthreads();

    f32x4 accI[8], accA[8];
#pragma unroll
    for (int jj = 0; jj < 8; ++jj) {
        accI[jj] = (f32x4){0.f, 0.f, 0.f, 0.f};
        accA[jj] = (f32x4){0.f, 0.f, 0.f, 0.f};
    }

    const int row = wave * 16 + fm;
#pragma unroll
    for (int s = 0; s < 4; ++s) {
        s16x8 af = *(const s16x8*)((char*)As + row * 256 + ((((s << 2) + q) ^ (row & 15)) << 4));
#pragma unroll
        for (int jj = 0; jj < 8; ++jj) {
            int wrow = jj * 16 + fm;
            s16x8 bw = *(const s16x8*)((char*)Ws + wrow * 256 + ((((s << 2) + q) ^ (wrow & 15)) << 4));
            accI[jj] = __builtin_amdgcn_mfma_f32_16x16x32_bf16(af, bw, accI[jj], 0, 0, 0);
        }
    }
    __syncthreads();  // all waves done reading Ws (gate 1)
    // 4. stage Ws for a gate
    const bf16* w1 = wT + (size_t)(NB_ + n) * 16384;
#pragma unroll
    for (int it = 0; it < 8; ++it) {
        int off = it * 4096 + tid * 16;
        int j = off >> 8;
        int g = ((off & 255) >> 4) ^ (j & 15);
        async_g2l(w1 + j * 128 + g * 8, (char*)Ws + off);
    }
    __syncthreads();
#pragma unroll
    for (int s = 0; s < 4; ++s) {
        s16x8 af = *(const s16x8*)((char*)As + row * 256 + ((((s << 2) + q) ^ (row & 15)) << 4));
#pragma unroll
        for (int jj = 0; jj < 8; ++jj) {
            int wrow = jj * 16 + fm;
            s16x8 bw = *(const s16x8*)((char*)Ws + wrow * 256 + ((((s << 2) + q) ^ (wrow & 15)) << 4));
            accA[jj] = __builtin_amdgcn_mfma_f32_16x16x32_bf16(af, bw, accA[jj], 0, 0, 0);
        }
    }
    __syncthreads();  // MFMA reads of As/Ws done; epilogue may overwrite both

    // 5. epilogue: C/D col=fm, row=q*4+rr. la/nx to global; a into a_sh; nx into own As slot
#pragma unroll
    for (int jj = 0; jj < 8; ++jj) {
        int col = jj * 16 + fm;
        int r = n * BW_ + col;
        float bi = igb[r], ba = agb[r];
        float s8 = sp8[r];
#pragma unroll
        for (int rr = 0; rr < 4; ++rr) {
            int rowl = wave * 16 + q * 4 + rr;
            short* slot = (short*)((char*)As + rowl * 256 +
                          ((((col >> 3)) ^ (rowl & 15)) << 4) + (col & 7) * 2);
            float xcv = b2f_s(*slot);
            float xg = accI[jj][rr] + bi;
            float ag = accA[jj][rr] + ba;
            float la = -s8 * sigm_fast(ag);
            float av = __expf(la);
            float t2 = 2.f * la;
            float nem = (t2 > -0.125f)
                ? -t2 * (1.f + t2 * (0.5f + t2 * (0.16666667f + t2 * 0.04166667f)))
                : 1.f - av * av;
            float nxv = xcv * sigm_fast(xg) * sqrtf(nem);
            short nxs = f2b_s(nxv);
            size_t o = (size_t)(mBase + rowl) * R_ + r;
            la_out[o] = __float2bfloat16(la);
            nx_out[o] = __builtin_bit_cast(bf16, (unsigned short)nxs);
            a_sh[rowl * 128 + col] = av;
            *slot = nxs;                       // same slot this thread read; no race
        }
    }
    __syncthreads();

    // 6. fused chunk scan: threads 0..127, one channel each, sequential over 64 rows
    if (tid < 128) {
        int col = tid;
        float h = 0.f, cum = 1.f;
#pragma unroll 4
        for (int t = 0; t < CHUNK; ++t) {
            float a = a_sh[t * 128 + col];
            float nxv = b2f_s(*(const short*)((char*)As + t * 256 +
                              ((((col >> 3)) ^ (t & 15)) << 4) + (col & 7) * 2));
            h = fmaf(a, h, nxv);
            cum *= a;
        }
        int b = mBase >> 12, c = (mBase & (S_ - 1)) >> 6;
        int so = ((b * NCH + c) << 11) + n * BW_ + col;
        Ach[so] = cum;
        Hla[so] = h;
    }
}

// carry into each chunk (sequential over 64 chunks, fp32)
__global__ __launch_bounds__(256) void scan_carry(const float* __restrict__ Ach,
                                                  const float* __restrict__ Hla,
                                                  float* __restrict__ carry) {
    int idx = blockIdx.x * 256 + threadIdx.x;  // B*R
    int r = idx & (R_ - 1), b = idx >> 11;
    float cy = 0.f;
    for (int c = 0; c < NCH; ++c) {
        int o = (b * NCH + c) * R_ + r;
        carry[o] = cy;
        cy = fmaf(Ach[o], cy, Hla[o]);
    }
}

// passB: re-run recurrence with carry folded in; g = gelu_exact(y)*h -> bf16
// y = columns [2048,4096) of xy
__global__ __launch_bounds__(256) void scan_passB(const bf16* __restrict__ la_buf,
                                                  const bf16* __restrict__ nx_buf,
                                                  const float* __restrict__ carry,
                                                  const bf16* __restrict__ xy,
                                                  bf16* __restrict__ g_out) {
    int bid = blockIdx.x;                 // B*NCH*8 = 1024
    int rt = bid & 7, c = (bid >> 3) & 63, b = bid >> 9;
    int r = rt * 256 + threadIdx.x;
    int m0 = b * S_ + c * CHUNK;
    size_t base = (size_t)m0 * R_ + r;
    const bf16* yp = xy + (size_t)m0 * 4096 + 2048 + r;
    int so = (b * NCH + c) * R_ + r;
    float h = carry[so];
    for (int t = 0; t < CHUNK; ++t) {
        size_t o = base + (size_t)t * R_;
        float a = __expf(__bfloat162float(la_buf[o]));
        float nx = __bfloat162float(nx_buf[o]);
        h = fmaf(a, h, nx);
        float y = __bfloat162float(yp[(size_t)t * 4096]);
        float g = 0.5f * y * (1.f + erff(y * 0.70710678f));
        g_out[o] = __float2bfloat16(g * h);
    }
}

extern "C" void kernel_launch(void* const* d_in, const int* in_sizes, int n_in,
                              void* d_out, int out_size, void* d_ws, size_t ws_size,
                              hipStream_t stream) {
    const float* x    = (const float*)d_in[0];
    const float* Wxy  = (const float*)d_in[1];
    const float* igw  = (const float*)d_in[2];
    const float* igb  = (const float*)d_in[3];
    const float* agw  = (const float*)d_in[4];
    const float* agb  = (const float*)d_in[5];
    const float* apar = (const float*)d_in[6];
    const float* cw   = (const float*)d_in[7];
    const float* cb   = (const float*)d_in[8];
    const float* Wres = (const float*)d_in[9];
    float* out = (float*)d_out;

    // Workspace (187 MiB), lifetime overlays:
    //   [0,32)    xbf  bf16 [M,H]   (dead after GEMM1)  -> la bf16 [M,R] (gate output)
    //   [32,48)   wxyb bf16 [2R,H]  (dead after GEMM1)  -> wT (1 MiB) + sp8
    //   [48,112)  xy   bf16 [M,4096] (xr|y); xr dead after gate, y until passB
    //   [112,120) wresb bf16
    //   [120,152) g    bf16 [M,R]  (passB output)
    //   [152,184) nx   bf16 [M,R]
    //   [184,187) Ach/Hla/carry fp32, 1 MiB each
    char* ws = (char*)d_ws;
    const size_t MiB = (size_t)1 << 20;
    bf16*  xbf   = (bf16*)(ws);
    bf16*  la    = (bf16*)(ws);               // overlay on xbf
    bf16*  wxyb  = (bf16*)(ws + 32 * MiB);
    bf16*  wT    = (bf16*)(ws + 32 * MiB);    // overlay (staged after GEMM1)
    float* sp8   = (float*)(ws + 33 * MiB + 65536);
    bf16*  xy    = (bf16*)(ws + 48 * MiB);
    bf16*  wresb = (bf16*)(ws + 112 * MiB);
    bf16*  g     = (bf16*)(ws + 120 * MiB);
    bf16*  nx    = (bf16*)(ws + 152 * MiB);
    float* Ach   = (float*)(ws + 184 * MiB);
    float* Hla   = (float*)(ws + 185 * MiB);
    float* cyb   = (float*)(ws + 186 * MiB);

    // merged casts to bf16
    cast_all<<<14336, 256, 0, stream>>>(x, Wxy, Wres, xbf, wxyb, wresb);

    // GEMM1 (merged): xy[M,4096] = x[M,2048] * Wxy[4096,2048]^T
    gemm_bt<bf16><<<dim3(32, 64), 256, 0, stream>>>(xbf, wxyb, xy, 2048, 2048, 2048, 4096);

    // gate prep (after GEMM1 so wT/sp8 can overlay wxyb)
    wcast_T<<<32, 256, 0, stream>>>(igw, agw, wT);
    sp8_kernel<<<8, 256, 0, stream>>>(apar, sp8);

    // fused conv + gates + chunk summaries -> la (overlays xbf), nx, Ach, Hla
    gate_kernel<<<dim3(NB_, 128), 256, 0, stream>>>(xy, cw, cb, wT, igb, agb, sp8,
                                                    la, nx, Ach, Hla);

    // carry scan + passB -> g
    scan_carry<<<16, 256, 0, stream>>>(Ach, Hla, cyb);
    scan_passB<<<1024, 256, 0, stream>>>(la, nx, cyb, xy, g);

    // GEMM2: out[M,H] = g[M,R] * Wres[H,R]^T  (fp32 out)
    gemm_bt<float><<<dim3(16, 64), 256, 0, stream>>>(g, wresb, out, 2048, 2048, 2048, 2048);
}

// Round 6
// 468.557 us; speedup vs baseline: 1.1918x; 1.1918x over previous
//
#include <hip/hip_runtime.h>
#include <hip/hip_bf16.h>

typedef __hip_bfloat16 bf16;
typedef __attribute__((ext_vector_type(8))) short s16x8;   // 8 bf16 (4 VGPRs) MFMA frag
typedef __attribute__((ext_vector_type(4))) float f32x4;   // MFMA accumulator

#define B_ 2
#define S_ 4096
#define H_ 2048
#define R_ 2048
#define M_ 8192      // B*S
#define NB_ 16
#define BW_ 128
#define CHUNK 64     // scan chunk length
#define NCH 64       // S/CHUNK

__device__ __forceinline__ short f2b_s(float f) {
    return (short)__builtin_bit_cast(unsigned short, __float2bfloat16(f));
}
__device__ __forceinline__ float b2f_s(short s) {
    unsigned int u = ((unsigned int)(unsigned short)s) << 16;
    return __builtin_bit_cast(float, u);
}
__device__ __forceinline__ float sigm_fast(float x) { return 1.f / (1.f + __expf(-x)); }

// async global->LDS, 16B per lane; LDS dest must be wave-uniform base + lane*16
__device__ __forceinline__ void async_g2l(const void* g, void* l) {
    __builtin_amdgcn_global_load_lds((const __attribute__((address_space(1))) void*)g,
                                     (__attribute__((address_space(3))) void*)l, 16, 0, 0);
}

// ---------------- merged cast fp32 -> bf16 for x / Wxy / Wres ----------------
// unit = 8 elems. x: 2097152 units, Wxy: 1048576, Wres: 524288 -> 3670016 total.
__global__ __launch_bounds__(256) void cast_all(const float* __restrict__ x,
                                                const float* __restrict__ wxy,
                                                const float* __restrict__ wres,
                                                bf16* __restrict__ xbf,
                                                bf16* __restrict__ wxyb,
                                                bf16* __restrict__ wresb) {
    int idx = blockIdx.x * 256 + threadIdx.x;
    const float* in; bf16* out; int off;
    if (idx < 2097152)      { in = x;    out = xbf;   off = idx; }
    else if (idx < 3145728) { in = wxy;  out = wxyb;  off = idx - 2097152; }
    else                    { in = wres; out = wresb; off = idx - 3145728; }
    size_t i8 = (size_t)off * 8;
    float4 v0 = *(const float4*)(in + i8);
    float4 v1 = *(const float4*)(in + i8 + 4);
    s16x8 o;
    o[0] = f2b_s(v0.x); o[1] = f2b_s(v0.y); o[2] = f2b_s(v0.z); o[3] = f2b_s(v0.w);
    o[4] = f2b_s(v1.x); o[5] = f2b_s(v1.y); o[6] = f2b_s(v1.z); o[7] = f2b_s(v1.w);
    *(s16x8*)(out + i8) = o;
}

// ---------------- transpose-cast gate weights via LDS tile ----------------
// grid 32: p = blk>>4, n = blk&15. wT[p][n][j][i] = w_p[n][i][j], bf16.
__global__ __launch_bounds__(256) void wcast_T(const float* __restrict__ igw,
                                               const float* __restrict__ agw,
                                               bf16* __restrict__ wT) {
    __shared__ float tile[128 * 129];
    int blk = blockIdx.x;
    int p = blk >> 4, n = blk & 15;
    const float* w = (p ? agw : igw) + (size_t)n * 16384;   // [i][j] row-major
    int tid = threadIdx.x;
#pragma unroll
    for (int it = 0; it < 64; ++it) {
        int u = it * 256 + tid;           // element: i = u>>7, j = u&127
        tile[(u >> 7) * 129 + (u & 127)] = w[u];
    }
    __syncthreads();
    bf16* o = wT + (size_t)blk * 16384;
#pragma unroll
    for (int it = 0; it < 64; ++it) {
        int u = it * 256 + tid;           // output elem: j = u>>7, i = u&127
        o[u] = __float2bfloat16(tile[(u & 127) * 129 + (u >> 7)]);
    }
}

// ---------------- sp8[r] = 8*softplus(a_param[r]) ----------------
__global__ __launch_bounds__(256) void sp8_kernel(const float* __restrict__ apar,
                                                  float* __restrict__ sp8) {
    int r = blockIdx.x * 256 + threadIdx.x;
    float ap = apar[r];
    sp8[r] = 8.f * (ap > 20.f ? ap : log1pf(expf(ap)));
}

// ---------------- generic NT GEMM: C[M,N] = A[M,K] * B[N,K]^T, bf16 in, OutT out ----
// 128x128 tile, BK=64, 4 waves 2x2, 64x64/wave, 16x16x32 MFMA, XOR-swizzled LDS,
// global_load_lds width=16 staging. launch_bounds(256,4): 4 blocks/CU.
// NOTE (R5 post-mortem): (256,5) forces ~102 regs/wave but acc needs 64 AGPR + 60 VGPR
// = 124 in gfx950's UNIFIED file -> scratch spills (+27 MB writes, 2x dur). Keep 4.
__device__ __forceinline__ void store_c(float* p, float v) { *p = v; }
__device__ __forceinline__ void store_c(bf16* p, float v) { *p = __float2bfloat16(v); }

template <typename OutT>
__global__ __launch_bounds__(256, 4) void gemm_bt(const bf16* __restrict__ A,
                                                  const bf16* __restrict__ Bm,
                                                  OutT* __restrict__ C,
                                                  int K, int lda, int ldb, int ldc) {
    __shared__ __align__(16) short As[128 * 64];
    __shared__ __align__(16) short Bs[128 * 64];
    const int tid = threadIdx.x;
    const int lane = tid & 63, wave = tid >> 6;
    const int waveM = wave >> 1, waveN = wave & 1;
    const int mBase = blockIdx.y * 128, nBase = blockIdx.x * 128;
    const int fm = lane & 15, q = lane >> 4;

    f32x4 acc[4][4];
#pragma unroll
    for (int i = 0; i < 4; ++i)
#pragma unroll
        for (int j = 0; j < 4; ++j) acc[i][j] = (f32x4){0.f, 0.f, 0.f, 0.f};

    for (int k0 = 0; k0 < K; k0 += 64) {
        __syncthreads();
#pragma unroll
        for (int it = 0; it < 4; ++it) {
            int off = it * 4096 + tid * 16;          // byte offset in tile (lane-contig)
            int r = off >> 7;                        // row
            int g = ((off & 127) >> 4) ^ (r & 7);    // source k-group for this slot
            async_g2l(A + (size_t)(mBase + r) * lda + k0 + g * 8, (char*)As + off);
            async_g2l(Bm + (size_t)(nBase + r) * ldb + k0 + g * 8, (char*)Bs + off);
        }
        __syncthreads();
#pragma unroll
        for (int s = 0; s < 2; ++s) {
            s16x8 af[4], bfr[4];
#pragma unroll
            for (int i = 0; i < 4; ++i) {
                int row = waveM * 64 + i * 16 + fm;
                af[i] = *(const s16x8*)((char*)As + row * 128 + ((((s << 2) + q) ^ (row & 7)) << 4));
                int col = waveN * 64 + i * 16 + fm;
                bfr[i] = *(const s16x8*)((char*)Bs + col * 128 + ((((s << 2) + q) ^ (col & 7)) << 4));
            }
#pragma unroll
            for (int i = 0; i < 4; ++i)
#pragma unroll
                for (int j = 0; j < 4; ++j)
                    acc[i][j] = __builtin_amdgcn_mfma_f32_16x16x32_bf16(af[i], bfr[j], acc[i][j], 0, 0, 0);
        }
    }
    // C/D layout: col=lane&15, row=q*4+reg (m89/m91-verified)
#pragma unroll
    for (int i = 0; i < 4; ++i) {
        int rowg = mBase + waveM * 64 + i * 16 + q * 4;
#pragma unroll
        for (int j = 0; j < 4; ++j) {
            int colg = nBase + waveN * 64 + j * 16 + fm;
#pragma unroll
            for (int rr = 0; rr < 4; ++rr)
                store_c(C + (size_t)(rowg + rr) * ldc + colg, acc[i][j][rr]);
        }
    }
}

// ------- fused: causal conv + block-diag dual gate GEMM + RG-LRU + chunk scan -------
// grid (NB_, M_/64): one block = one (batch, 64-step chunk, 128-channel block).
// Stages 67 rows of xy (conv window), computes xc in LDS, runs both gate GEMMs,
// writes la (bf16), nx (bf16), chunk summaries Ach/Hla (fp32).
__global__ __launch_bounds__(256) void gate_kernel(const bf16* __restrict__ xy,
                                                   const float* __restrict__ cw,
                                                   const float* __restrict__ cb,
                                                   const bf16* __restrict__ wT,
                                                   const float* __restrict__ igb,
                                                   const float* __restrict__ agb,
                                                   const float* __restrict__ sp8,
                                                   bf16* __restrict__ la_out,
                                                   bf16* __restrict__ nx_out,
                                                   float* __restrict__ Ach,
                                                   float* __restrict__ Hla) {
    __shared__ __align__(16) short As[64 * 128];     // 16 KB; xc tile -> nx tile
    __shared__ __align__(16) char  Wmem[128 * 256];  // 32 KB; Xs raw -> W tile -> a[64][128] f32
    short* Xs   = (short*)Wmem;                      // 67 rows x 128 shorts (raw xy window)
    short* Ws   = (short*)Wmem;
    float* a_sh = (float*)Wmem;
    const int n = blockIdx.x;
    const int mBase = blockIdx.y * 64;
    const int tid = threadIdx.x;
    const int lane = tid & 63, wave = tid >> 6;
    const int fm = lane & 15, q = lane >> 4;
    const int t0 = mBase & (S_ - 1);

    // 1. stage xy window: rows rr=0..66 <-> m = mBase + rr - 3 (zero outside batch)
#pragma unroll
    for (int it = 0; it < 5; ++it) {
        int u = it * 256 + tid;              // (rr, gg): rr = u>>4, gg = u&15
        if (u < 67 * 16) {
            int rr = u >> 4, gg = u & 15;
            s16x8 v = (s16x8){0, 0, 0, 0, 0, 0, 0, 0};
            if (t0 != 0 || rr >= 3) {
                int m = mBase + rr - 3;
                v = *(const s16x8*)(xy + (size_t)m * 4096 + n * BW_ + gg * 8);
            }
            *(s16x8*)((char*)Xs + u * 16) = v;
        }
    }
    __syncthreads();

    // 2. conv into As (swizzled bf16): thread = (col, row-half), sliding 4-tap window
    {
        int col = tid & 127, rh = tid >> 7;
        int rbase = n * BW_ + col;
        float w0c = cw[rbase], w1c = cw[R_ + rbase], w2c = cw[2 * R_ + rbase],
              w3c = cw[3 * R_ + rbase];
        float bc = cb[rbase];
        int r0 = rh * 32;
        float xm3 = b2f_s(Xs[(r0 + 0) * 128 + col]);
        float xm2 = b2f_s(Xs[(r0 + 1) * 128 + col]);
        float xm1 = b2f_s(Xs[(r0 + 2) * 128 + col]);
#pragma unroll
        for (int rw = 0; rw < 32; ++rw) {
            int row = r0 + rw;
            float x0 = b2f_s(Xs[(row + 3) * 128 + col]);
            float v = bc + w0c * xm3 + w1c * xm2 + w2c * xm1 + w3c * x0;
            xm3 = xm2; xm2 = xm1; xm1 = x0;
            *(short*)((char*)As + row * 256 + ((((col >> 3)) ^ (row & 15)) << 4) +
                      (col & 7) * 2) = f2b_s(v);
        }
    }
    __syncthreads();   // As ready; Xs region dead

    // 3. stage Ws for input gate
    const bf16* w0 = wT + (size_t)n * 16384;
#pragma unroll
    for (int it = 0; it < 8; ++it) {
        int off = it * 4096 + tid * 16;
        int j = off >> 8;
        int g = ((off & 255) >> 4) ^ (j & 15);
        async_g2l(w0 + j * 128 + g * 8, (char*)Ws + off);
    }
    __syncthreads();

    f32x4 accI[8], accA[8];
#pragma unroll
    for (int jj = 0; jj < 8; ++jj) {
        accI[jj] = (f32x4){0.f, 0.f, 0.f, 0.f};
        accA[jj] = (f32x4){0.f, 0.f, 0.f, 0.f};
    }

    const int row = wave * 16 + fm;
#pragma unroll
    for (int s = 0; s < 4; ++s) {
        s16x8 af = *(const s16x8*)((char*)As + row * 256 + ((((s << 2) + q) ^ (row & 15)) << 4));
#pragma unroll
        for (int jj = 0; jj < 8; ++jj) {
            int wrow = jj * 16 + fm;
            s16x8 bw = *(const s16x8*)((char*)Ws + wrow * 256 + ((((s << 2) + q) ^ (wrow & 15)) << 4));
            accI[jj] = __builtin_amdgcn_mfma_f32_16x16x32_bf16(af, bw, accI[jj], 0, 0, 0);
        }
    }
    __syncthreads();  // all waves done reading Ws (gate 1)
    // 4. stage Ws for a gate
    const bf16* w1 = wT + (size_t)(NB_ + n) * 16384;
#pragma unroll
    for (int it = 0; it < 8; ++it) {
        int off = it * 4096 + tid * 16;
        int j = off >> 8;
        int g = ((off & 255) >> 4) ^ (j & 15);
        async_g2l(w1 + j * 128 + g * 8, (char*)Ws + off);
    }
    __syncthreads();
#pragma unroll
    for (int s = 0; s < 4; ++s) {
        s16x8 af = *(const s16x8*)((char*)As + row * 256 + ((((s << 2) + q) ^ (row & 15)) << 4));
#pragma unroll
        for (int jj = 0; jj < 8; ++jj) {
            int wrow = jj * 16 + fm;
            s16x8 bw = *(const s16x8*)((char*)Ws + wrow * 256 + ((((s << 2) + q) ^ (wrow & 15)) << 4));
            accA[jj] = __builtin_amdgcn_mfma_f32_16x16x32_bf16(af, bw, accA[jj], 0, 0, 0);
        }
    }
    __syncthreads();  // MFMA reads of As/Ws done; epilogue may overwrite both

    // 5. epilogue: C/D col=fm, row=q*4+rr. la/nx to global; a into a_sh; nx into own As slot
#pragma unroll
    for (int jj = 0; jj < 8; ++jj) {
        int col = jj * 16 + fm;
        int r = n * BW_ + col;
        float bi = igb[r], ba = agb[r];
        float s8 = sp8[r];
#pragma unroll
        for (int rr = 0; rr < 4; ++rr) {
            int rowl = wave * 16 + q * 4 + rr;
            short* slot = (short*)((char*)As + rowl * 256 +
                          ((((col >> 3)) ^ (rowl & 15)) << 4) + (col & 7) * 2);
            float xcv = b2f_s(*slot);
            float xg = accI[jj][rr] + bi;
            float ag = accA[jj][rr] + ba;
            float la = -s8 * sigm_fast(ag);
            float av = __expf(la);
            float t2 = 2.f * la;
            float nem = (t2 > -0.125f)
                ? -t2 * (1.f + t2 * (0.5f + t2 * (0.16666667f + t2 * 0.04166667f)))
                : 1.f - av * av;
            float nxv = xcv * sigm_fast(xg) * sqrtf(nem);
            short nxs = f2b_s(nxv);
            size_t o = (size_t)(mBase + rowl) * R_ + r;
            la_out[o] = __float2bfloat16(la);
            nx_out[o] = __builtin_bit_cast(bf16, (unsigned short)nxs);
            a_sh[rowl * 128 + col] = av;
            *slot = nxs;                       // same slot this thread read; no race
        }
    }
    __syncthreads();

    // 6. fused chunk scan: threads 0..127, one channel each, sequential over 64 rows
    if (tid < 128) {
        int col = tid;
        float h = 0.f, cum = 1.f;
#pragma unroll 4
        for (int t = 0; t < CHUNK; ++t) {
            float a = a_sh[t * 128 + col];
            float nxv = b2f_s(*(const short*)((char*)As + t * 256 +
                              ((((col >> 3)) ^ (t & 15)) << 4) + (col & 7) * 2));
            h = fmaf(a, h, nxv);
            cum *= a;
        }
        int b = mBase >> 12, c = (mBase & (S_ - 1)) >> 6;
        int so = ((b * NCH + c) << 11) + n * BW_ + col;
        Ach[so] = cum;
        Hla[so] = h;
    }
}

// carry into each chunk (sequential over 64 chunks, fp32)
__global__ __launch_bounds__(256) void scan_carry(const float* __restrict__ Ach,
                                                  const float* __restrict__ Hla,
                                                  float* __restrict__ carry) {
    int idx = blockIdx.x * 256 + threadIdx.x;  // B*R
    int r = idx & (R_ - 1), b = idx >> 11;
    float cy = 0.f;
    for (int c = 0; c < NCH; ++c) {
        int o = (b * NCH + c) * R_ + r;
        carry[o] = cy;
        cy = fmaf(Ach[o], cy, Hla[o]);
    }
}

// passB: re-run recurrence with carry folded in; g = gelu_exact(y)*h -> bf16
// y = columns [2048,4096) of xy
__global__ __launch_bounds__(256) void scan_passB(const bf16* __restrict__ la_buf,
                                                  const bf16* __restrict__ nx_buf,
                                                  const float* __restrict__ carry,
                                                  const bf16* __restrict__ xy,
                                                  bf16* __restrict__ g_out) {
    int bid = blockIdx.x;                 // B*NCH*8 = 1024
    int rt = bid & 7, c = (bid >> 3) & 63, b = bid >> 9;
    int r = rt * 256 + threadIdx.x;
    int m0 = b * S_ + c * CHUNK;
    size_t base = (size_t)m0 * R_ + r;
    const bf16* yp = xy + (size_t)m0 * 4096 + 2048 + r;
    int so = (b * NCH + c) * R_ + r;
    float h = carry[so];
    for (int t = 0; t < CHUNK; ++t) {
        size_t o = base + (size_t)t * R_;
        float a = __expf(__bfloat162float(la_buf[o]));
        float nx = __bfloat162float(nx_buf[o]);
        h = fmaf(a, h, nx);
        float y = __bfloat162float(yp[(size_t)t * 4096]);
        float g = 0.5f * y * (1.f + erff(y * 0.70710678f));
        g_out[o] = __float2bfloat16(g * h);
    }
}

extern "C" void kernel_launch(void* const* d_in, const int* in_sizes, int n_in,
                              void* d_out, int out_size, void* d_ws, size_t ws_size,
                              hipStream_t stream) {
    const float* x    = (const float*)d_in[0];
    const float* Wxy  = (const float*)d_in[1];
    const float* igw  = (const float*)d_in[2];
    const float* igb  = (const float*)d_in[3];
    const float* agw  = (const float*)d_in[4];
    const float* agb  = (const float*)d_in[5];
    const float* apar = (const float*)d_in[6];
    const float* cw   = (const float*)d_in[7];
    const float* cb   = (const float*)d_in[8];
    const float* Wres = (const float*)d_in[9];
    float* out = (float*)d_out;

    // Workspace (187 MiB), lifetime overlays:
    //   [0,32)    xbf  bf16 [M,H]   (dead after GEMM1)  -> la bf16 [M,R] (gate output)
    //   [32,48)   wxyb bf16 [2R,H]  (dead after GEMM1)  -> wT (1 MiB) + sp8
    //   [48,112)  xy   bf16 [M,4096] (xr|y); xr dead after gate, y until passB
    //   [112,120) wresb bf16
    //   [120,152) g    bf16 [M,R]  (passB output)
    //   [152,184) nx   bf16 [M,R]
    //   [184,187) Ach/Hla/carry fp32, 1 MiB each
    char* ws = (char*)d_ws;
    const size_t MiB = (size_t)1 << 20;
    bf16*  xbf   = (bf16*)(ws);
    bf16*  la    = (bf16*)(ws);               // overlay on xbf
    bf16*  wxyb  = (bf16*)(ws + 32 * MiB);
    bf16*  wT    = (bf16*)(ws + 32 * MiB);    // overlay (staged after GEMM1)
    float* sp8   = (float*)(ws + 33 * MiB + 65536);
    bf16*  xy    = (bf16*)(ws + 48 * MiB);
    bf16*  wresb = (bf16*)(ws + 112 * MiB);
    bf16*  g     = (bf16*)(ws + 120 * MiB);
    bf16*  nx    = (bf16*)(ws + 152 * MiB);
    float* Ach   = (float*)(ws + 184 * MiB);
    float* Hla   = (float*)(ws + 185 * MiB);
    float* cyb   = (float*)(ws + 186 * MiB);

    // merged casts to bf16
    cast_all<<<14336, 256, 0, stream>>>(x, Wxy, Wres, xbf, wxyb, wresb);

    // GEMM1 (merged): xy[M,4096] = x[M,2048] * Wxy[4096,2048]^T
    gemm_bt<bf16><<<dim3(32, 64), 256, 0, stream>>>(xbf, wxyb, xy, 2048, 2048, 2048, 4096);

    // gate prep (after GEMM1 so wT/sp8 can overlay wxyb)
    wcast_T<<<32, 256, 0, stream>>>(igw, agw, wT);
    sp8_kernel<<<8, 256, 0, stream>>>(apar, sp8);

    // fused conv + gates + chunk summaries -> la (overlays xbf), nx, Ach, Hla
    gate_kernel<<<dim3(NB_, 128), 256, 0, stream>>>(xy, cw, cb, wT, igb, agb, sp8,
                                                    la, nx, Ach, Hla);

    // carry scan + passB -> g
    scan_carry<<<16, 256, 0, stream>>>(Ach, Hla, cyb);
    scan_passB<<<1024, 256, 0, stream>>>(la, nx, cyb, xy, g);

    // GEMM2: out[M,H] = g[M,R] * Wres[H,R]^T  (fp32 out)
    gemm_bt<float><<<dim3(16, 64), 256, 0, stream>>>(g, wresb, out, 2048, 2048, 2048, 2048);
}